// Round 2
// baseline (936.786 us; speedup 1.0000x reference)
//
#include <hip/hip_runtime.h>
#include <stdint.h>

// AdjAttenAggr: out = softmax(mask? NEG : (Q K^T / 16)) @ (diag(fix) other)
// Q = main@Wq^T+bq [8192,256], K = other@Wk^T+bk [8192,256]
// Strategy: bf16 MFMA everywhere; flash-style fused kernel, no A materialization.
// Round 2: adaptive mask dtype (bool/int32/float32 detected on device).

typedef short short8 __attribute__((ext_vector_type(8)));
typedef float f32x4 __attribute__((ext_vector_type(4)));

#define N_ROWS 8192
#define M_COLS 8192
#define QK_DIM 512
#define MID_D  256
#define OUT_D  512

__device__ __forceinline__ unsigned short f2b(float f) {
  union { float f; unsigned u; } x; x.f = f;
  unsigned r = x.u + 0x7FFFu + ((x.u >> 16) & 1u);   // RNE bf16
  return (unsigned short)(r >> 16);
}
__device__ __forceinline__ float b2f(unsigned short b) {
  union { unsigned u; float f; } x; x.u = ((unsigned)b) << 16;
  return x.f;
}

__device__ __forceinline__ f32x4 mfma16(short8 a, short8 b, f32x4 c) {
  return __builtin_amdgcn_mfma_f32_16x16x32_bf16(a, b, c, 0, 0, 0);
}

__device__ __forceinline__ void gload_lds16(const void* g, void* l) {
  __builtin_amdgcn_global_load_lds(
      (const __attribute__((address_space(1))) unsigned int*)g,
      (__attribute__((address_space(3))) unsigned int*)l, 16, 0, 0);
}

// ---- detect mask element layout (bool 1B / int32 / float32) ------------
// Writes params[0]=stride (bytes per element), params[1]=byte offset of a
// byte that is nonzero iff the element is nonzero (little-endian).
__global__ void detect_mask(const unsigned char* __restrict__ mask,
                            int* __restrict__ params) {
  __shared__ int s_gt1, s_nzoff;
  if (threadIdx.x == 0) { s_gt1 = 0; s_nzoff = 0; }
  __syncthreads();
  int gt1 = 0, nz = 0;
  for (int i = threadIdx.x; i < 65536; i += 256) {
    unsigned char b = mask[i];
    if (b > 1) gt1 = 1;
    if ((i & 3) && b) nz = 1;
  }
  if (gt1) atomicOr(&s_gt1, 1);
  if (nz) atomicOr(&s_nzoff, 1);
  __syncthreads();
  if (threadIdx.x == 0) {
    int stride, off;
    if (s_gt1)        { stride = 4; off = 3; }  // float32: 1.0f -> byte3 = 0x3F
    else if (s_nzoff) { stride = 1; off = 0; }  // bool bytes
    else              { stride = 4; off = 0; }  // int32 LE low byte
    params[0] = stride; params[1] = off;
  }
}

// ---- prep: Wq/Wk f32 -> bf16 -------------------------------------------
__global__ void prep_w(const float* __restrict__ Wq, const float* __restrict__ Wk,
                       unsigned short* __restrict__ Wqb, unsigned short* __restrict__ Wkb) {
  int b = blockIdx.x;
  const float* src = (b < 64) ? Wq : Wk;
  unsigned short* dst = (b < 64) ? Wqb : Wkb;
  int off = ((b & 63) * 256 + threadIdx.x) * 8;
  float4 v0 = *(const float4*)(src + off);
  float4 v1 = *(const float4*)(src + off + 4);
  alignas(16) unsigned short o[8] = {f2b(v0.x), f2b(v0.y), f2b(v0.z), f2b(v0.w),
                                     f2b(v1.x), f2b(v1.y), f2b(v1.z), f2b(v1.w)};
  *(short8*)(dst + off) = *(const short8*)o;
}

// ---- prep: Vt[j][m] = bf16(fix[m]*other[m][j]) (transposed) ------------
__global__ void prep_vt(const float* __restrict__ other, const float* __restrict__ fix,
                        unsigned short* __restrict__ Vt) {
  __shared__ unsigned short T[64][72];   // +8 pad
  int m0 = blockIdx.x * 64, j0 = blockIdx.y * 64;
  int t = threadIdx.x;
  {
    int mr = t >> 2, jc = (t & 3) * 16;
    float f = fix[m0 + mr];
    const float* src = other + (size_t)(m0 + mr) * QK_DIM + j0 + jc;
    #pragma unroll
    for (int i = 0; i < 16; i += 4) {
      float4 v = *(const float4*)(src + i);
      T[mr][jc + i + 0] = f2b(v.x * f);
      T[mr][jc + i + 1] = f2b(v.y * f);
      T[mr][jc + i + 2] = f2b(v.z * f);
      T[mr][jc + i + 3] = f2b(v.w * f);
    }
  }
  __syncthreads();
  {
    int jr = t >> 2, mc = (t & 3) * 16;
    alignas(16) unsigned short o[16];
    #pragma unroll
    for (int i = 0; i < 16; ++i) o[i] = T[mc + i][jr];
    unsigned short* dst = Vt + (size_t)(j0 + jr) * M_COLS + m0 + mc;
    *(short8*)dst       = *(const short8*)o;
    *(short8*)(dst + 8) = *(const short8*)(o + 8);
  }
}

// ---- projection GEMM: Out[8192,256] = bf16(X[8192,512] @ Wb^T + bias) --
__global__ __launch_bounds__(256, 2) void proj_kernel(
    const float* __restrict__ X, const unsigned short* __restrict__ Wb,
    const float* __restrict__ bias, unsigned short* __restrict__ Out) {
  int lane = threadIdx.x & 63, wv = threadIdx.x >> 6;
  int l15 = lane & 15, l4 = lane >> 4;
  int rows0 = blockIdx.x * 64 + wv * 16;
  const float* xrow = X + (size_t)(rows0 + l15) * QK_DIM + l4 * 8;
  f32x4 acc[16];
  #pragma unroll
  for (int cg = 0; cg < 16; ++cg) acc[cg] = (f32x4){0.f, 0.f, 0.f, 0.f};
  for (int kk = 0; kk < 16; ++kk) {
    float4 a0 = *(const float4*)(xrow + kk * 32);
    float4 a1 = *(const float4*)(xrow + kk * 32 + 4);
    alignas(16) unsigned short ab[8] = {f2b(a0.x), f2b(a0.y), f2b(a0.z), f2b(a0.w),
                                        f2b(a1.x), f2b(a1.y), f2b(a1.z), f2b(a1.w)};
    short8 a = *(const short8*)ab;
    const unsigned short* wb = Wb + (size_t)l15 * QK_DIM + kk * 32 + l4 * 8;
    #pragma unroll
    for (int cg = 0; cg < 16; ++cg) {
      short8 b = *(const short8*)(wb + (size_t)cg * 16 * QK_DIM);
      acc[cg] = mfma16(a, b, acc[cg]);
    }
  }
  #pragma unroll
  for (int cg = 0; cg < 16; ++cg) {
    int j = cg * 16 + l15;
    float bj = bias[j];
    #pragma unroll
    for (int r = 0; r < 4; ++r) {
      int row = rows0 + l4 * 4 + r;
      Out[(size_t)row * MID_D + j] = f2b(acc[cg][r] + bj);
    }
  }
}

// ---- fused flash kernel ------------------------------------------------
// BM=32 rows/wg, KVT=64 kv-cols/step, 8 waves.
// wave wv: S-role (rg=wv>>2, mg=wv&3) computes one 16x16 S frag/step;
//          PV-role: out cols [wv*64, wv*64+64).
__global__ __launch_bounds__(512, 2) void fused_kernel(
    const unsigned short* __restrict__ Qb, const unsigned short* __restrict__ Kb,
    const unsigned short* __restrict__ Vt, const unsigned char* __restrict__ mask,
    const int* __restrict__ mparams, float* __restrict__ out) {
  __shared__ unsigned short Klds[64 * 256];  // 32KB, XOR-swizzled ((m&7)<<4 on byte addr)
  __shared__ unsigned short Plds[32 * 64];   // 4KB,  XOR-swizzled ((n&7)<<4)
  __shared__ float rs_lds[4][32];
  __shared__ float inv_lds[32];

  const int tid = threadIdx.x;
  const int lane = tid & 63, wv = tid >> 6;
  const int l15 = lane & 15, l4 = lane >> 4;
  const int rg = wv >> 2, mg = wv & 3;
  const int n0 = blockIdx.x * 32;

  const size_t mstride = (size_t)mparams[0];
  const size_t moff = (size_t)mparams[1];

  // Q rows rg*16+l15, k = kk*32 + l4*8 .. +8 : held in registers
  short8 qf[8];
  {
    const unsigned short* q = Qb + (size_t)(n0 + rg * 16 + l15) * MID_D + l4 * 8;
    #pragma unroll
    for (int kk = 0; kk < 8; ++kk) qf[kk] = *(const short8*)(q + kk * 32);
  }

  f32x4 O[2][4];
  #pragma unroll
  for (int og = 0; og < 2; ++og)
    #pragma unroll
    for (int cg = 0; cg < 4; ++cg) O[og][cg] = (f32x4){0.f, 0.f, 0.f, 0.f};
  float rs[4] = {0.f, 0.f, 0.f, 0.f};

  const unsigned char* mbase =
      mask + ((size_t)(n0 + rg * 16 + l4 * 4) * M_COLS + mg * 16 + l15) * mstride + moff;

  for (int m0 = 0; m0 < M_COLS; m0 += 64) {
    // --- stage K-tile [64][256] via global_load_lds, source pre-swizzled ---
    #pragma unroll
    for (int i = 0; i < 4; ++i) {
      int c = (wv * 4 + i) * 64 + lane;       // 16B-chunk index 0..2047
      int m = c >> 5, d16 = c & 31;
      gload_lds16(Kb + (size_t)(m0 + m) * MID_D + ((d16 ^ (m & 7)) << 3),
                  &Klds[(wv * 4 + i) * 512]);
    }
    unsigned int mk[4];
    #pragma unroll
    for (int r = 0; r < 4; ++r) mk[r] = mbase[((size_t)r * M_COLS + m0) * mstride];

    __syncthreads();  // prev PV done (Plds free) + K loads drained (vmcnt 0)

    // --- S phase: one 16x16 frag per wave ---
    f32x4 s = {0.f, 0.f, 0.f, 0.f};
    {
      int m = mg * 16 + l15;
      const char* kbase = (const char*)Klds + m * 512;
      int sw = (m & 7) << 4;
      #pragma unroll
      for (int kk = 0; kk < 8; ++kk) {
        short8 b = *(const short8*)(kbase + (((kk * 32 + l4 * 8) * 2) ^ sw));
        s = mfma16(qf[kk], b, s);
      }
    }
    #pragma unroll
    for (int r = 0; r < 4; ++r) {
      int n = rg * 16 + l4 * 4 + r;
      float e = mk[r] ? 0.f : __expf(s[r] * 0.0625f);  // exp(S/16); masked -> 0
      unsigned short pb = f2b(e);
      rs[r] += b2f(pb);   // denominator consistent with bf16 numerator
      int m = mg * 16 + l15;
      *(unsigned short*)((char*)Plds + ((n * 128 + m * 2) ^ ((n & 7) << 4))) = pb;
    }
    __syncthreads();  // P complete

    // --- PV phase: O[32 x 64(wave)] += P[32 x 64] @ V[64 x 64(wave)] ---
    #pragma unroll
    for (int mm = 0; mm < 2; ++mm) {
      int krel = mm * 32 + l4 * 8;
      int nA = l15, nB = 16 + l15;
      short8 a0 = *(const short8*)((const char*)Plds + ((nA * 128 + krel * 2) ^ ((nA & 7) << 4)));
      short8 a1 = *(const short8*)((const char*)Plds + ((nB * 128 + krel * 2) ^ ((nB & 7) << 4)));
      const unsigned short* vb = Vt + (size_t)(wv * 64 + l15) * M_COLS + m0 + krel;
      #pragma unroll
      for (int cg = 0; cg < 4; ++cg) {
        short8 b = *(const short8*)(vb + (size_t)cg * 16 * M_COLS);  // global, L2/L3-hot
        O[0][cg] = mfma16(a0, b, O[0][cg]);
        O[1][cg] = mfma16(a1, b, O[1][cg]);
      }
    }
    // loop: next gload_lds overwrites Klds — safe: all S-phase reads of Klds
    // finished before barrier2, and stores are issued after passing it.
  }

  // --- rowsum reduce (16 lanes of same quarter share a row-class) ---
  #pragma unroll
  for (int r = 0; r < 4; ++r) {
    float v = rs[r];
    v += __shfl_xor(v, 1); v += __shfl_xor(v, 2);
    v += __shfl_xor(v, 4); v += __shfl_xor(v, 8);
    rs[r] = v;
  }
  if (l15 == 0) {
    #pragma unroll
    for (int r = 0; r < 4; ++r) rs_lds[mg][rg * 16 + l4 * 4 + r] = rs[r];
  }
  __syncthreads();
  if (tid < 32) {
    float t = rs_lds[0][tid] + rs_lds[1][tid] + rs_lds[2][tid] + rs_lds[3][tid];
    inv_lds[tid] = 1.0f / t;
  }
  __syncthreads();

  #pragma unroll
  for (int og = 0; og < 2; ++og) {
    #pragma unroll
    for (int r = 0; r < 4; ++r) {
      float iv = inv_lds[og * 16 + l4 * 4 + r];
      float* orow = out + (size_t)(n0 + og * 16 + l4 * 4 + r) * OUT_D + wv * 64 + l15;
      #pragma unroll
      for (int cg = 0; cg < 4; ++cg) orow[cg * 16] = O[og][cg][r] * iv;
    }
  }
}

// ---- launcher ----------------------------------------------------------
extern "C" void kernel_launch(void* const* d_in, const int* in_sizes, int n_in,
                              void* d_out, int out_size, void* d_ws, size_t ws_size,
                              hipStream_t stream) {
  const float* main_feat = (const float*)d_in[0];
  const float* other     = (const float*)d_in[1];
  const float* fix       = (const float*)d_in[2];
  const unsigned char* mask = (const unsigned char*)d_in[3];  // layout detected on device
  const float* Wq = (const float*)d_in[4];
  const float* bq = (const float*)d_in[5];
  const float* Wk = (const float*)d_in[6];
  const float* bk = (const float*)d_in[7];
  float* out = (float*)d_out;

  char* ws = (char*)d_ws;
  unsigned short* Qb  = (unsigned short*)(ws);                          // 4 MB
  unsigned short* Kb  = (unsigned short*)(ws + ((size_t)4 << 20));      // 4 MB
  unsigned short* Vt  = (unsigned short*)(ws + ((size_t)8 << 20));      // 8 MB
  unsigned short* Wqb = (unsigned short*)(ws + ((size_t)16 << 20));     // 256 KB
  unsigned short* Wkb = (unsigned short*)(ws + ((size_t)16 << 20) + (1 << 19));
  int* mparams        = (int*)(ws + ((size_t)16 << 20) + ((size_t)3 << 19));

  detect_mask<<<1, 256, 0, stream>>>(mask, mparams);
  prep_w<<<128, 256, 0, stream>>>(Wq, Wk, Wqb, Wkb);
  prep_vt<<<dim3(128, 8), 256, 0, stream>>>(other, fix, Vt);
  proj_kernel<<<128, 256, 0, stream>>>(main_feat, Wqb, bq, Qb);
  proj_kernel<<<128, 256, 0, stream>>>(other, Wkb, bk, Kb);
  fused_kernel<<<256, 512, 0, stream>>>(Qb, Kb, Vt, mask, mparams, out);
}

// Round 5
// 675.152 us; speedup vs baseline: 1.3875x; 1.3875x over previous
//
#include <hip/hip_runtime.h>
#include <stdint.h>

// AdjAttenAggr: out = softmax(mask? NEG : (Q K^T / 16)) @ (diag(fix) other)
// Round 3 kernel, resubmit #2 (GPU broker timeouts in rounds 3 & 4; this
// source has never run). BM=64 rows/wg, 1024 threads (16 waves), KV-split
// MS=4 with XCD-affine slice assignment, partial-O + combine pass.

typedef short short8 __attribute__((ext_vector_type(8)));
typedef float f32x4 __attribute__((ext_vector_type(4)));

#define N_ROWS 8192
#define M_COLS 8192
#define QK_DIM 512
#define MID_D  256
#define OUT_D  512

__device__ __forceinline__ unsigned short f2b(float f) {
  union { float f; unsigned u; } x; x.f = f;
  unsigned r = x.u + 0x7FFFu + ((x.u >> 16) & 1u);   // RNE bf16
  return (unsigned short)(r >> 16);
}
__device__ __forceinline__ float b2f(unsigned short b) {
  union { unsigned u; float f; } x; x.u = ((unsigned)b) << 16;
  return x.f;
}

__device__ __forceinline__ f32x4 mfma16(short8 a, short8 b, f32x4 c) {
  return __builtin_amdgcn_mfma_f32_16x16x32_bf16(a, b, c, 0, 0, 0);
}

__device__ __forceinline__ void gload_lds16(const void* g, void* l) {
  __builtin_amdgcn_global_load_lds(
      (const __attribute__((address_space(1))) unsigned int*)g,
      (__attribute__((address_space(3))) unsigned int*)l, 16, 0, 0);
}

// ---- detect mask element layout (bool 1B / int32 / float32) ------------
__global__ void detect_mask(const unsigned int* __restrict__ mask32,
                            int* __restrict__ params) {
  __shared__ int s_gt1, s_nzoff;
  if (threadIdx.x == 0) { s_gt1 = 0; s_nzoff = 0; }
  __syncthreads();
  int gt1 = 0, nz = 0;
  for (int i = threadIdx.x; i < 16384; i += 256) {   // 64KB scan
    unsigned w = mask32[i];
    #pragma unroll
    for (int k = 0; k < 4; ++k) {
      unsigned b = (w >> (8 * k)) & 0xFFu;
      if (b > 1) gt1 = 1;
      if (k && b) nz = 1;
    }
  }
  if (gt1) atomicOr(&s_gt1, 1);
  if (nz) atomicOr(&s_nzoff, 1);
  __syncthreads();
  if (threadIdx.x == 0) {
    int stride, off;
    if (s_gt1)        { stride = 4; off = 3; }  // float32: 1.0f -> byte3 = 0x3F
    else if (s_nzoff) { stride = 1; off = 0; }  // bool bytes
    else              { stride = 4; off = 0; }  // int32 LE low byte
    params[0] = stride; params[1] = off;
  }
}

// ---- prep: Wq/Wk f32 -> bf16 -------------------------------------------
__global__ void prep_w(const float* __restrict__ Wq, const float* __restrict__ Wk,
                       unsigned short* __restrict__ Wqb, unsigned short* __restrict__ Wkb) {
  int b = blockIdx.x;
  const float* src = (b < 64) ? Wq : Wk;
  unsigned short* dst = (b < 64) ? Wqb : Wkb;
  int off = ((b & 63) * 256 + threadIdx.x) * 8;
  float4 v0 = *(const float4*)(src + off);
  float4 v1 = *(const float4*)(src + off + 4);
  alignas(16) unsigned short o[8] = {f2b(v0.x), f2b(v0.y), f2b(v0.z), f2b(v0.w),
                                     f2b(v1.x), f2b(v1.y), f2b(v1.z), f2b(v1.w)};
  *(short8*)(dst + off) = *(const short8*)o;
}

// ---- prep: Vt[j][m] = bf16(fix[m]*other[m][j]) (transposed) ------------
__global__ void prep_vt(const float* __restrict__ other, const float* __restrict__ fix,
                        unsigned short* __restrict__ Vt) {
  __shared__ unsigned short T[64][72];   // +8 pad
  int m0 = blockIdx.x * 64, j0 = blockIdx.y * 64;
  int t = threadIdx.x;
  {
    int mr = t >> 2, jc = (t & 3) * 16;
    float f = fix[m0 + mr];
    const float* src = other + (size_t)(m0 + mr) * QK_DIM + j0 + jc;
    #pragma unroll
    for (int i = 0; i < 16; i += 4) {
      float4 v = *(const float4*)(src + i);
      T[mr][jc + i + 0] = f2b(v.x * f);
      T[mr][jc + i + 1] = f2b(v.y * f);
      T[mr][jc + i + 2] = f2b(v.z * f);
      T[mr][jc + i + 3] = f2b(v.w * f);
    }
  }
  __syncthreads();
  {
    int jr = t >> 2, mc = (t & 3) * 16;
    alignas(16) unsigned short o[16];
    #pragma unroll
    for (int i = 0; i < 16; ++i) o[i] = T[mc + i][jr];
    unsigned short* dst = Vt + (size_t)(j0 + jr) * M_COLS + m0 + mc;
    *(short8*)dst       = *(const short8*)o;
    *(short8*)(dst + 8) = *(const short8*)(o + 8);
  }
}

// ---- projection GEMM: Out[8192,256] = bf16(X[8192,512] @ Wb^T + bias) --
// grid 256: block b -> rows (b>>1)*64, cols (b&1)*128
__global__ __launch_bounds__(256, 2) void proj_kernel(
    const float* __restrict__ X, const unsigned short* __restrict__ Wb,
    const float* __restrict__ bias, unsigned short* __restrict__ Out) {
  int lane = threadIdx.x & 63, wv = threadIdx.x >> 6;
  int l15 = lane & 15, l4 = lane >> 4;
  int rows0 = (blockIdx.x >> 1) * 64 + wv * 16;
  int ch = (blockIdx.x & 1) * 128;
  const float* xrow = X + (size_t)(rows0 + l15) * QK_DIM + l4 * 8;
  f32x4 acc[8];
  #pragma unroll
  for (int cg = 0; cg < 8; ++cg) acc[cg] = (f32x4){0.f, 0.f, 0.f, 0.f};
  for (int kk = 0; kk < 16; ++kk) {
    float4 a0 = *(const float4*)(xrow + kk * 32);
    float4 a1 = *(const float4*)(xrow + kk * 32 + 4);
    alignas(16) unsigned short ab[8] = {f2b(a0.x), f2b(a0.y), f2b(a0.z), f2b(a0.w),
                                        f2b(a1.x), f2b(a1.y), f2b(a1.z), f2b(a1.w)};
    short8 a = *(const short8*)ab;
    const unsigned short* wb = Wb + (size_t)(ch + l15) * QK_DIM + kk * 32 + l4 * 8;
    #pragma unroll
    for (int cg = 0; cg < 8; ++cg) {
      short8 b = *(const short8*)(wb + (size_t)cg * 16 * QK_DIM);
      acc[cg] = mfma16(a, b, acc[cg]);
    }
  }
  #pragma unroll
  for (int cg = 0; cg < 8; ++cg) {
    int j = ch + cg * 16 + l15;
    float bj = bias[j];
    #pragma unroll
    for (int r = 0; r < 4; ++r) {
      int row = rows0 + l4 * 4 + r;
      Out[(size_t)row * MID_D + j] = f2b(acc[cg][r] + bj);
    }
  }
}

// ---- fused flash kernel ------------------------------------------------
// BM=64 Q-rows/wg, KVT=64/step, 16 waves. blk = rb*MS + ms (ms = XCD-affine
// kv-slice). S: wave (rg=wv>>2, mg=wv&3) one 16x16 frag. PV: wave owns out
// cols [wv*32, wv*32+32). Partials: Op[blk][64][512], rsp[ms][8192].
__global__ __launch_bounds__(1024, 4) void fused_kernel(
    const unsigned short* __restrict__ Qb, const unsigned short* __restrict__ Kb,
    const unsigned short* __restrict__ Vt, const unsigned char* __restrict__ mask,
    const int* __restrict__ mparams, float* __restrict__ Op,
    float* __restrict__ rsp, int msLog, int kvlen) {
  __shared__ unsigned short Klds[64 * 256];  // 32KB, XOR-swizzled ((m&7)<<4 byte)
  __shared__ unsigned short Plds[64 * 64];   // 8KB,  XOR-swizzled ((n&7)<<4 byte)
  __shared__ float rs_lds[4][64];

  const int tid = threadIdx.x;
  const int lane = tid & 63, wv = tid >> 6;
  const int l15 = lane & 15, l4 = lane >> 4;
  const int rg = wv >> 2, mg = wv & 3;
  const int ms = blockIdx.x & ((1 << msLog) - 1);
  const int rb = blockIdx.x >> msLog;
  const int n0 = rb * 64;
  const int kv0 = ms * kvlen;

  const size_t mstride = (size_t)mparams[0];
  const size_t moff = (size_t)mparams[1];

  // Q rows rg*16+l15 in registers
  short8 qf[8];
  {
    const unsigned short* q = Qb + (size_t)(n0 + rg * 16 + l15) * MID_D + l4 * 8;
    #pragma unroll
    for (int kk = 0; kk < 8; ++kk) qf[kk] = *(const short8*)(q + kk * 32);
  }

  f32x4 O[4][2];
  #pragma unroll
  for (int g = 0; g < 4; ++g)
    #pragma unroll
    for (int c = 0; c < 2; ++c) O[g][c] = (f32x4){0.f, 0.f, 0.f, 0.f};
  float rs[4] = {0.f, 0.f, 0.f, 0.f};

  const unsigned char* mbase =
      mask + ((size_t)(n0 + rg * 16 + l4 * 4) * M_COLS + kv0 + mg * 16 + l15) * mstride + moff;
  const unsigned short* kvK = Kb + (size_t)kv0 * MID_D;
  const unsigned short* kvV = Vt + kv0;   // col offset into Vt rows

  for (int m0 = 0; m0 < kvlen; m0 += 64) {
    // --- stage K-tile [64][256] via global_load_lds, source pre-swizzled ---
    #pragma unroll
    for (int i = 0; i < 2; ++i) {
      int c = i * 1024 + tid;                 // 16B-chunk index 0..2047
      int m = c >> 5, d16 = c & 31;
      gload_lds16(kvK + (size_t)(m0 + m) * MID_D + ((d16 ^ (m & 7)) << 3),
                  &Klds[(size_t)c * 8]);
    }
    unsigned int mk[4];
    #pragma unroll
    for (int r = 0; r < 4; ++r) mk[r] = mbase[((size_t)r * M_COLS + m0) * mstride];

    __syncthreads();  // prev PV done (Plds free) + K loads drained

    // --- S phase: one 16x16 frag per wave ---
    f32x4 s = {0.f, 0.f, 0.f, 0.f};
    {
      int m = mg * 16 + l15;
      const char* kb = (const char*)Klds + m * 512;
      int sw = (m & 7) << 4;
      #pragma unroll
      for (int kk = 0; kk < 8; ++kk) {
        short8 b = *(const short8*)(kb + (((kk * 32 + l4 * 8) * 2) ^ sw));
        s = mfma16(qf[kk], b, s);
      }
    }
    #pragma unroll
    for (int r = 0; r < 4; ++r) {
      int n = rg * 16 + l4 * 4 + r;
      float e = mk[r] ? 0.f : __expf(s[r] * 0.0625f);  // exp(S/16); masked -> 0
      unsigned short pb = f2b(e);
      rs[r] += b2f(pb);   // denominator consistent with bf16 numerator
      *(unsigned short*)((char*)Plds +
          ((n * 128 + (mg * 16 + l15) * 2) ^ ((n & 7) << 4))) = pb;
    }
    __syncthreads();  // P complete

    // --- PV phase: O[64 x 32(wave)] += P[64 x 64] @ V[64 x 32(wave)] ---
    #pragma unroll
    for (int mm = 0; mm < 2; ++mm) {
      int krel = mm * 32 + l4 * 8;
      short8 a[4];
      #pragma unroll
      for (int g = 0; g < 4; ++g) {
        int n = g * 16 + l15;
        a[g] = *(const short8*)((const char*)Plds + ((n * 128 + krel * 2) ^ ((n & 7) << 4)));
      }
      short8 b0 = *(const short8*)(kvV + (size_t)(wv * 32 + l15) * M_COLS + m0 + krel);
      short8 b1 = *(const short8*)(kvV + (size_t)(wv * 32 + 16 + l15) * M_COLS + m0 + krel);
      #pragma unroll
      for (int g = 0; g < 4; ++g) {
        O[g][0] = mfma16(a[g], b0, O[g][0]);
        O[g][1] = mfma16(a[g], b1, O[g][1]);
      }
    }
  }

  // --- rowsum reduce: sum over l15 within wave, then over 4 mg waves ---
  #pragma unroll
  for (int r = 0; r < 4; ++r) {
    float v = rs[r];
    v += __shfl_xor(v, 1); v += __shfl_xor(v, 2);
    v += __shfl_xor(v, 4); v += __shfl_xor(v, 8);
    rs[r] = v;
  }
  if (l15 == 0) {
    #pragma unroll
    for (int r = 0; r < 4; ++r) rs_lds[mg][rg * 16 + l4 * 4 + r] = rs[r];
  }
  __syncthreads();
  if (tid < 64) {
    float t = rs_lds[0][tid] + rs_lds[1][tid] + rs_lds[2][tid] + rs_lds[3][tid];
    rsp[(size_t)ms * N_ROWS + n0 + tid] = t;
  }

  // --- write O partial (un-normalized) ---
  float* ob = Op + (size_t)blockIdx.x * (64 * 512);
  #pragma unroll
  for (int g = 0; g < 4; ++g) {
    #pragma unroll
    for (int r = 0; r < 4; ++r) {
      float* row = ob + (size_t)(g * 16 + l4 * 4 + r) * 512 + wv * 32 + l15;
      row[0]  = O[g][0][r];
      row[16] = O[g][1][r];
    }
  }
}

// ---- combine: out = (sum_ms Op) / (sum_ms rsp) -------------------------
__global__ void combine_kernel(const float* __restrict__ Op, const float* __restrict__ rsp,
                               float* __restrict__ out, int MS) {
  int gid = blockIdx.x * 256 + threadIdx.x;   // 8192*128
  int n = gid >> 7;
  int j = (gid & 127) << 2;
  int rb = n >> 6, r = n & 63;
  float a0 = 0.f, a1 = 0.f, a2 = 0.f, a3 = 0.f, d = 0.f;
  for (int ms = 0; ms < MS; ++ms) {
    const float* p = Op + (((size_t)rb * MS + ms) * 64 + r) * 512 + j;
    float4 v = *(const float4*)p;
    a0 += v.x; a1 += v.y; a2 += v.z; a3 += v.w;
    d += rsp[(size_t)ms * N_ROWS + n];
  }
  float inv = 1.0f / d;
  float4 o; o.x = a0 * inv; o.y = a1 * inv; o.z = a2 * inv; o.w = a3 * inv;
  *(float4*)(out + (size_t)n * OUT_D + j) = o;
}

// ---- launcher ----------------------------------------------------------
extern "C" void kernel_launch(void* const* d_in, const int* in_sizes, int n_in,
                              void* d_out, int out_size, void* d_ws, size_t ws_size,
                              hipStream_t stream) {
  const float* main_feat = (const float*)d_in[0];
  const float* other     = (const float*)d_in[1];
  const float* fix       = (const float*)d_in[2];
  const unsigned char* mask = (const unsigned char*)d_in[3];
  const float* Wq = (const float*)d_in[4];
  const float* bq = (const float*)d_in[5];
  const float* Wk = (const float*)d_in[6];
  const float* bk = (const float*)d_in[7];
  float* out = (float*)d_out;

  char* ws = (char*)d_ws;
  unsigned short* Qb  = (unsigned short*)(ws);                               // 4 MB
  unsigned short* Kb  = (unsigned short*)(ws + ((size_t)4 << 20));           // 4 MB
  unsigned short* Vt  = (unsigned short*)(ws + ((size_t)8 << 20));           // 8 MB
  unsigned short* Wqb = (unsigned short*)(ws + ((size_t)16 << 20));          // 256 KB
  unsigned short* Wkb = (unsigned short*)(ws + ((size_t)16 << 20) + (256 << 10));
  int* mparams        = (int*)(ws + ((size_t)16 << 20) + (512 << 10));
  float* rsp          = (float*)(ws + ((size_t)16 << 20) + (768 << 10));     // <=128 KB
  float* OpWs         = (float*)(ws + ((size_t)17 << 20));

  // Tier the KV-split by available workspace (Op = MS*16MB at 17MB base).
  int msLog; float* Op;
  size_t base = (size_t)17 << 20;
  if (ws_size >= base + ((size_t)64 << 20))      { msLog = 2; Op = OpWs; }
  else if (ws_size >= base + ((size_t)32 << 20)) { msLog = 1; Op = OpWs; }
  else                                           { msLog = 0; Op = out; }
  int MS = 1 << msLog;
  int kvlen = M_COLS >> msLog;

  detect_mask<<<1, 256, 0, stream>>>((const unsigned int*)mask, mparams);
  prep_w<<<128, 256, 0, stream>>>(Wq, Wk, Wqb, Wkb);
  prep_vt<<<dim3(128, 8), 256, 0, stream>>>(other, fix, Vt);
  proj_kernel<<<256, 256, 0, stream>>>(main_feat, Wqb, bq, Qb);
  proj_kernel<<<256, 256, 0, stream>>>(other, Wkb, bk, Kb);
  fused_kernel<<<128 * MS, 1024, 0, stream>>>(Qb, Kb, Vt, mask, mparams,
                                              Op, rsp, msLog, kvlen);
  combine_kernel<<<4096, 256, 0, stream>>>(Op, rsp, out, MS);
}